// Round 1
// baseline (628.367 us; speedup 1.0000x reference)
//
#include <hip/hip_runtime.h>
#include <math.h>

#define BB 64
#define HH 1024
#define KK 1024

// d_out layout (floats): h_t | C_t | n_t | m_t
#define OFF_H ((size_t)0)
#define OFF_C ((size_t)BB * HH)
#define OFF_N (OFF_C + (size_t)BB * HH * HH)
#define OFF_M (OFF_N + (size_t)BB * HH)

__device__ __forceinline__ float dot4(float4 a, float4 b) {
    return a.x * b.x + a.y * b.y + a.z * b.z + a.w * b.w;
}

// Kernel 1: six fused GEMVs per (b,h) + pointwise epilogue.
// grid = (HH/4, BB), block = 256 (4 waves). Wave w handles h = bx*4+w, batch b = by.
// Each W row is read exactly once (coalesced float4). x row hits L1 after first wave.
__global__ __launch_bounds__(256) void k1_gemm_act(
    const float* __restrict__ x, const float* __restrict__ n_in, const float* __restrict__ m_in,
    const float* __restrict__ Wi, const float* __restrict__ bi,
    const float* __restrict__ Wf, const float* __restrict__ bf,
    const float* __restrict__ Wo, const float* __restrict__ bo,
    const float* __restrict__ Wq, const float* __restrict__ bq,
    const float* __restrict__ Wk, const float* __restrict__ bk,
    const float* __restrict__ Wv, const float* __restrict__ bv,
    float* __restrict__ out,
    float* __restrict__ f_s, float* __restrict__ iv_s, float* __restrict__ o_s,
    float* __restrict__ k_s, float* __restrict__ q_s, float* __restrict__ ni)
{
    const int b    = blockIdx.y;
    const int wave = threadIdx.x >> 6;
    const int lane = threadIdx.x & 63;
    const int h    = blockIdx.x * 4 + wave;

    const float4* xr  = (const float4*)(x  + (size_t)b * KK);
    const float4* wri = (const float4*)(Wi + (size_t)h * KK);
    const float4* wrf = (const float4*)(Wf + (size_t)h * KK);
    const float4* wro = (const float4*)(Wo + (size_t)h * KK);
    const float4* wrq = (const float4*)(Wq + (size_t)h * KK);
    const float4* wrk = (const float4*)(Wk + (size_t)h * KK);
    const float4* wrv = (const float4*)(Wv + (size_t)h * KK);

    float a0 = 0.f, a1 = 0.f, a2 = 0.f, a3 = 0.f, a4 = 0.f, a5 = 0.f;
#pragma unroll
    for (int c = 0; c < 4; ++c) {
        const int idx = c * 64 + lane;      // 256 float4 per row, coalesced
        const float4 xv = xr[idx];
        a0 += dot4(xv, wri[idx]);
        a1 += dot4(xv, wrf[idx]);
        a2 += dot4(xv, wro[idx]);
        a3 += dot4(xv, wrq[idx]);
        a4 += dot4(xv, wrk[idx]);
        a5 += dot4(xv, wrv[idx]);
    }
#pragma unroll
    for (int off = 32; off >= 1; off >>= 1) {
        a0 += __shfl_xor(a0, off, 64);
        a1 += __shfl_xor(a1, off, 64);
        a2 += __shfl_xor(a2, off, 64);
        a3 += __shfl_xor(a3, off, 64);
        a4 += __shfl_xor(a4, off, 64);
        a5 += __shfl_xor(a5, off, 64);
    }

    __shared__ float snq[4];
    if (lane == 0) {
        const size_t bh = (size_t)b * HH + h;
        const float it  = a0 + bi[h];
        const float ft  = a1 + bf[h];
        const float ot  = a2 + bo[h];
        const float qt  = a3 + bq[h];
        const float kt  = (a4 + bk[h]) * 0.03125f;   // / sqrt(1024)
        const float vt  = a5 + bv[h];

        const float fsig = 1.0f / (1.0f + __expf(-ft) * 0.0f + expf(-ft)); // keep precise expf
        // numerically stable log(sigmoid(ft))
        const float lsf = (ft >= 0.0f) ? -log1pf(expf(-ft)) : (ft - log1pf(expf(ft)));
        const float mt  = fmaxf(lsf + m_in[bh], it);
        const float ip  = expf(it - mt);
        const float nt  = fsig * n_in[bh] + ip * kt;
        const float osg = 1.0f / (1.0f + expf(-ot));

        out[OFF_N + bh] = nt;
        out[OFF_M + bh] = mt;
        f_s[bh]  = fsig;
        iv_s[bh] = ip * vt;
        o_s[bh]  = osg;
        k_s[bh]  = kt;
        q_s[bh]  = qt;
        snq[wave] = nt * qt;
    }
    __syncthreads();
    if (threadIdx.x == 0) {
        atomicAdd(ni + b, snq[0] + snq[1] + snq[2] + snq[3]);
    }
}

// Kernel 2: C_t = f*C + (i'*v)*k^T fused with h_tilda row-dot against q.
// grid = B*H blocks (one per C row), block = 256 threads, float4 per thread.
__global__ __launch_bounds__(256) void k2_fastweight(
    const float* __restrict__ C,
    const float* __restrict__ f_s, const float* __restrict__ iv_s,
    const float* __restrict__ o_s, const float* __restrict__ k_s,
    const float* __restrict__ q_s, const float* __restrict__ ni,
    float* __restrict__ out)
{
    const int row = blockIdx.x;          // row = b*H + i
    const int b   = row >> 10;
    const int t   = threadIdx.x;

    const float f  = f_s[row];
    const float iv = iv_s[row];

    const float4* Cr = (const float4*)(C + (size_t)row * HH);
    const float4* kr = (const float4*)(k_s + (size_t)b * HH);
    const float4* qr = (const float4*)(q_s + (size_t)b * HH);
    float4* Ct = (float4*)(out + OFF_C + (size_t)row * HH);

    const float4 c4 = Cr[t];
    const float4 k4 = kr[t];
    const float4 q4 = qr[t];

    float4 o;
    o.x = f * c4.x + iv * k4.x;
    o.y = f * c4.y + iv * k4.y;
    o.z = f * c4.z + iv * k4.z;
    o.w = f * c4.w + iv * k4.w;
    Ct[t] = o;

    float d = dot4(o, q4);
#pragma unroll
    for (int off = 32; off >= 1; off >>= 1) d += __shfl_xor(d, off, 64);

    __shared__ float sd[4];
    if ((t & 63) == 0) sd[t >> 6] = d;
    __syncthreads();
    if (t == 0) {
        const float tot = sd[0] + sd[1] + sd[2] + sd[3];
        const float div = fmaxf(fabsf(ni[b]), 1.0f);
        out[OFF_H + row] = o_s[row] * tot / div;
    }
}

extern "C" void kernel_launch(void* const* d_in, const int* in_sizes, int n_in,
                              void* d_out, int out_size, void* d_ws, size_t ws_size,
                              hipStream_t stream) {
    const float* x  = (const float*)d_in[0];
    const float* C  = (const float*)d_in[1];
    const float* n  = (const float*)d_in[2];
    const float* m  = (const float*)d_in[3];
    const float* Wi = (const float*)d_in[4];  const float* bi = (const float*)d_in[5];
    const float* Wf = (const float*)d_in[6];  const float* bf = (const float*)d_in[7];
    const float* Wo = (const float*)d_in[8];  const float* bo = (const float*)d_in[9];
    const float* Wq = (const float*)d_in[10]; const float* bq = (const float*)d_in[11];
    const float* Wk = (const float*)d_in[12]; const float* bk = (const float*)d_in[13];
    const float* Wv = (const float*)d_in[14]; const float* bv = (const float*)d_in[15];

    float* out = (float*)d_out;
    float* ws  = (float*)d_ws;
    float* f_s  = ws;
    float* iv_s = ws + (size_t)BB * HH;
    float* o_s  = ws + (size_t)2 * BB * HH;
    float* k_s  = ws + (size_t)3 * BB * HH;
    float* q_s  = ws + (size_t)4 * BB * HH;
    float* ni   = ws + (size_t)5 * BB * HH;

    hipMemsetAsync(ni, 0, BB * sizeof(float), stream);

    dim3 g1(HH / 4, BB);
    k1_gemm_act<<<g1, 256, 0, stream>>>(x, n, m, Wi, bi, Wf, bf, Wo, bo,
                                        Wq, bq, Wk, bk, Wv, bv,
                                        out, f_s, iv_s, o_s, k_s, q_s, ni);

    k2_fastweight<<<BB * HH, 256, 0, stream>>>(C, f_s, iv_s, o_s, k_s, q_s, ni, out);
}